// Round 8
// baseline (499.777 us; speedup 1.0000x reference)
//
#include <hip/hip_runtime.h>

#define N_NODES 100000
#define N_EDGES 1600000
#define IN_F    128
#define NEG_SLOPE 0.2f
#define NBUCK   512                 // scan width; active buckets = 391
#define PCHUNK  4096                // edges per partition block

__device__ __forceinline__ float bf2f(unsigned short u) {
    return __uint_as_float(((unsigned int)u) << 16);
}

// f32 -> bf16 round-to-nearest-even
__device__ __forceinline__ unsigned short f2bf(float f) {
    unsigned int u = __float_as_uint(f);
    u += 0x7FFFu + ((u >> 16) & 1u);
    return (unsigned short)(u >> 16);
}

// ---------------------------------------------------------------------------
// Fused GEMM hidden layers: featb(bf16) = A @ W (128x128), el/er in epilogue.
// Scalar-k loop: VGPR ~64, no spills (x4 unroll spilled at 256 VGPR, round 5).
// ---------------------------------------------------------------------------
__global__ __launch_bounds__(256) void gemm128_fused(const float* __restrict__ A,
                                                     const float* __restrict__ W,
                                                     const float* __restrict__ al,
                                                     const float* __restrict__ ar,
                                                     unsigned short* __restrict__ featb,
                                                     float* __restrict__ el,
                                                     float* __restrict__ er,
                                                     int nrows) {
    __shared__ float sH[64][IN_F];
    const int t    = threadIdx.x;
    const int row0 = blockIdx.x * 64;

#pragma unroll
    for (int i = 0; i < 8; ++i) {
        int e4 = i * 256 + t;
        int r  = (e4 * 4) >> 7;
        int c  = (e4 * 4) & 127;
        float4 v = make_float4(0.f, 0.f, 0.f, 0.f);
        int gr = row0 + r;
        if (gr < nrows) v = *(const float4*)(A + (size_t)gr * IN_F + c);
        *(float4*)(&sH[r][c]) = v;
    }
    __syncthreads();

    const int tx  = t & 31;
    const int ty  = t >> 5;
    const int col = tx * 4;

    float4 acc[8];
#pragma unroll
    for (int i = 0; i < 8; ++i) acc[i] = make_float4(0.f, 0.f, 0.f, 0.f);

    for (int k = 0; k < IN_F; ++k) {
        float4 b = *(const float4*)(W + k * 128 + col);
#pragma unroll
        for (int i = 0; i < 8; ++i) {
            float a = sH[ty * 8 + i][k];
            acc[i].x += a * b.x;
            acc[i].y += a * b.y;
            acc[i].z += a * b.z;
            acc[i].w += a * b.w;
        }
    }

    const float4 alv = *(const float4*)(al + col);
    const float4 arv = *(const float4*)(ar + col);
    const int h = tx >> 3;

#pragma unroll
    for (int i = 0; i < 8; ++i) {
        int r = row0 + ty * 8 + i;
        float4 a = acc[i];
        if (r < nrows) {
            ushort4 u;
            u.x = f2bf(a.x); u.y = f2bf(a.y); u.z = f2bf(a.z); u.w = f2bf(a.w);
            *(ushort4*)(featb + (size_t)r * 128 + col) = u;
        }
        float pel = a.x * alv.x + a.y * alv.y + a.z * alv.z + a.w * alv.w;
        float per = a.x * arv.x + a.y * arv.y + a.z * arv.z + a.w * arv.w;
        pel += __shfl_down(pel, 4); per += __shfl_down(per, 4);
        pel += __shfl_down(pel, 2); per += __shfl_down(per, 2);
        pel += __shfl_down(pel, 1); per += __shfl_down(per, 1);
        if ((tx & 7) == 0 && r < nrows) {
            el[r * 4 + h] = pel;
            er[r * 4 + h] = per;
        }
    }
}

// ---------------------------------------------------------------------------
// Dual GEMM layer 2: feat2b(bf16) = A @ W2, res2(f32) = A @ resW2, el/er fused.
// sH padded +4 so 8 distinct rows/wave hit distinct banks.
// ---------------------------------------------------------------------------
__global__ __launch_bounds__(256) void gemm16_dual(const float* __restrict__ A,
                                                   const float* __restrict__ W2,
                                                   const float* __restrict__ resW2,
                                                   const float* __restrict__ al,
                                                   const float* __restrict__ ar,
                                                   unsigned short* __restrict__ feat2b,
                                                   float* __restrict__ res2,
                                                   float* __restrict__ el,
                                                   float* __restrict__ er,
                                                   int nrows) {
    __shared__ float sH[64][IN_F + 4];
    const int t    = threadIdx.x;
    const int row0 = blockIdx.x * 64;

#pragma unroll
    for (int i = 0; i < 8; ++i) {
        int e4 = i * 256 + t;
        int r  = (e4 * 4) >> 7;
        int c  = (e4 * 4) & 127;
        float4 v = make_float4(0.f, 0.f, 0.f, 0.f);
        int gr = row0 + r;
        if (gr < nrows) v = *(const float4*)(A + (size_t)gr * IN_F + c);
        *(float4*)(&sH[r][c]) = v;
    }
    __syncthreads();

    const int tx   = t & 7;
    const int ty   = t >> 3;
    const bool isW = tx < 4;
    const int col  = (isW ? tx : tx - 4) * 4;
    const float* Wp = isW ? W2 : resW2;

    float4 acc[2];
    acc[0] = make_float4(0.f, 0.f, 0.f, 0.f);
    acc[1] = make_float4(0.f, 0.f, 0.f, 0.f);

    for (int k = 0; k < IN_F; ++k) {
        float4 b = *(const float4*)(Wp + k * 16 + col);
#pragma unroll
        for (int i = 0; i < 2; ++i) {
            float a = sH[ty * 2 + i][k];
            acc[i].x += a * b.x;
            acc[i].y += a * b.y;
            acc[i].z += a * b.z;
            acc[i].w += a * b.w;
        }
    }

    const float4 alv = isW ? *(const float4*)(al + col) : make_float4(0, 0, 0, 0);
    const float4 arv = isW ? *(const float4*)(ar + col) : make_float4(0, 0, 0, 0);

#pragma unroll
    for (int i = 0; i < 2; ++i) {
        int r = row0 + ty * 2 + i;
        float4 a = acc[i];
        if (isW) {
            if (r < nrows) {
                ushort4 u;
                u.x = f2bf(a.x); u.y = f2bf(a.y); u.z = f2bf(a.z); u.w = f2bf(a.w);
                *(ushort4*)(feat2b + (size_t)r * 16 + col) = u;
            }
            float pel = a.x * alv.x + a.y * alv.y + a.z * alv.z + a.w * alv.w;
            float per = a.x * arv.x + a.y * arv.y + a.z * arv.z + a.w * arv.w;
            pel += __shfl_down(pel, 2); per += __shfl_down(per, 2);
            pel += __shfl_down(pel, 1); per += __shfl_down(per, 1);
            if (tx == 0 && r < nrows) { el[r] = pel; er[r] = per; }
        } else if (r < nrows) {
            *(float4*)(res2 + (size_t)r * 16 + col) = a;
        }
    }
}

// ---------------------------------------------------------------------------
// CSR build, locality-aware. Bucket = dst>>8 (256-node windows, 391 active).
// ---------------------------------------------------------------------------
__global__ __launch_bounds__(256) void bucket_count_k(const int* __restrict__ dst,
                                                      int* __restrict__ bcount, int nE) {
    __shared__ int hist[NBUCK];
    const int t = threadIdx.x;
    hist[t] = 0; hist[t + 256] = 0;
    __syncthreads();
    const int start = blockIdx.x * PCHUNK;
#pragma unroll
    for (int j = 0; j < PCHUNK / 256; ++j) {
        int e = start + j * 256 + t;
        if (e < nE) atomicAdd(&hist[dst[e] >> 8], 1);
    }
    __syncthreads();
    if (hist[t])       atomicAdd(&bcount[t],       hist[t]);
    if (hist[t + 256]) atomicAdd(&bcount[t + 256], hist[t + 256]);
}

__global__ __launch_bounds__(NBUCK) void scan512(const int* __restrict__ bcount,
                                                 int* __restrict__ bbase,
                                                 int* __restrict__ bcursor) {
    __shared__ int s[NBUCK];
    const int t = threadIdx.x;
    int v = bcount[t];
    s[t] = v;
    __syncthreads();
#pragma unroll
    for (int off = 1; off < NBUCK; off <<= 1) {
        int x = (t >= off) ? s[t - off] : 0;
        __syncthreads();
        s[t] += x;
        __syncthreads();
    }
    int excl = s[t] - v;
    bbase[t]   = excl;
    bcursor[t] = excl;
}

__global__ __launch_bounds__(512) void partition_k(const int* __restrict__ src,
                                                   const int* __restrict__ dst,
                                                   int* __restrict__ bcursor,
                                                   uint2* __restrict__ pe, int nE) {
    __shared__ int   hist[NBUCK];
    __shared__ int   lstart[NBUCK];
    __shared__ int   gbase[NBUCK];
    __shared__ int   curB[NBUCK];
    __shared__ uint2 reorder[PCHUNK];

    const int t = threadIdx.x;
    const int start = blockIdx.x * PCHUNK;
    const int m = min(PCHUNK, nE - start);

    hist[t] = 0;
    __syncthreads();

#pragma unroll
    for (int j = 0; j < PCHUNK / 512; ++j) {
        int e = start + j * 512 + t;
        if (e < nE) atomicAdd(&hist[dst[e] >> 8], 1);
    }
    __syncthreads();
    const int cnt = hist[t];

    __shared__ int s[NBUCK];
    s[t] = cnt;
    __syncthreads();
#pragma unroll
    for (int off = 1; off < NBUCK; off <<= 1) {
        int x = (t >= off) ? s[t - off] : 0;
        __syncthreads();
        s[t] += x;
        __syncthreads();
    }
    lstart[t] = s[t] - cnt;
    curB[t]   = s[t] - cnt;
    gbase[t] = cnt ? atomicAdd(&bcursor[t], cnt) : 0;
    __syncthreads();

#pragma unroll
    for (int j = 0; j < PCHUNK / 512; ++j) {
        int e = start + j * 512 + t;
        if (e < nE) {
            int d = dst[e];
            int pos = atomicAdd(&curB[d >> 8], 1);
            reorder[pos] = make_uint2((unsigned)src[e], (unsigned)d);
        }
    }
    __syncthreads();

    for (int i = t; i < m; i += 512) {
        uint2 ed = reorder[i];
        int b = (int)(ed.y >> 8);
        pe[gbase[b] + (i - lstart[b])] = ed;
    }
}

__global__ __launch_bounds__(256) void bucket_finalize(const uint2* __restrict__ pe,
                                                       const int* __restrict__ bbase,
                                                       int* __restrict__ rowptr,
                                                       int* __restrict__ deg,
                                                       int* __restrict__ sorted_src,
                                                       int nE) {
    __shared__ int deg_l[256];
    __shared__ int s[256];
    __shared__ int cur[256];

    const int b  = blockIdx.x;
    const int t  = threadIdx.x;
    const int base = bbase[b];
    const int endE = (b + 1 < NBUCK) ? bbase[b + 1] : nE;
    const int cnt  = endE - base;
    const int n    = b * 256 + t;

    deg_l[t] = 0;
    __syncthreads();
    for (int i = t; i < cnt; i += 256)
        atomicAdd(&deg_l[pe[base + i].y & 255u], 1);
    __syncthreads();

    const int dv = deg_l[t];
    s[t] = dv;
    __syncthreads();
#pragma unroll
    for (int off = 1; off < 256; off <<= 1) {
        int x = (t >= off) ? s[t - off] : 0;
        __syncthreads();
        s[t] += x;
        __syncthreads();
    }
    const int off_l = s[t] - dv;
    if (n < N_NODES) {
        rowptr[n] = base + off_l;
        deg[n]    = dv;
    }
    cur[t] = off_l;
    __syncthreads();

    for (int i = t; i < cnt; i += 256) {
        uint2 ed = pe[base + i];
        int pos = atomicAdd(&cur[ed.y & 255u], 1);
        sorted_src[base + pos] = (int)ed.x;
    }
}

// ---------------------------------------------------------------------------
// Pull aggregation, H=4, D=32 (128 feats), bf16 gathers, wave per node.
// TWO edges per iteration: half-wave 0 (lanes 0-31) takes even staged edges,
// half-wave 1 odd; each lane owns a feature QUAD (ushort4 = 8B dwordx2).
// Cross-half shfl(32) merges edge parities + completes den. Fused
// /den + residual + relu epilogue, float4 store by lanes 0-31.
// ---------------------------------------------------------------------------
__global__ __launch_bounds__(256) void gat_agg128(const int* __restrict__ rowptr,
                                                  const int* __restrict__ deg,
                                                  const int* __restrict__ sorted_src,
                                                  const float* __restrict__ el,
                                                  const float* __restrict__ er,
                                                  const unsigned short* __restrict__ featb,
                                                  const float* __restrict__ res,
                                                  float* __restrict__ out) {
    __shared__ int   sS[4][64];
    __shared__ float sW[4][64][4];

    const int wv   = threadIdx.x >> 6;
    const int lane = threadIdx.x & 63;
    const int nd   = blockIdx.x * 4 + wv;
    const int half = lane >> 5;          // edge parity owned by this half-wave
    const int l32  = lane & 31;
    const int f0   = l32 * 4;            // feature quad base
    const int h    = l32 >> 3;           // head of this quad

    const int dg = deg[nd];
    const int r0 = rowptr[nd];
    const float4 er4 = *(const float4*)(er + nd * 4);

    float den = 0.f;
    float ax = 0.f, ay = 0.f, az = 0.f, aw = 0.f;

    for (int base = 0; base < dg; base += 64) {
        int m = dg - base; if (m > 64) m = 64;
        if (lane < m) {
            int s = sorted_src[r0 + base + lane];
            sS[wv][lane] = s;
            float4 e4 = *(const float4*)(el + s * 4);
            float4 w;
            float v;
            v = e4.x + er4.x; v = v > 0.f ? v : NEG_SLOPE * v; w.x = __expf(v);
            v = e4.y + er4.y; v = v > 0.f ? v : NEG_SLOPE * v; w.y = __expf(v);
            v = e4.z + er4.z; v = v > 0.f ? v : NEG_SLOPE * v; w.z = __expf(v);
            v = e4.w + er4.w; v = v > 0.f ? v : NEG_SLOPE * v; w.w = __expf(v);
            *(float4*)(&sW[wv][lane][0]) = w;
        }
        // wave-synchronous LDS (same wave wrote it)
        for (int i = half; i < m; i += 2) {
            int s   = sS[wv][i];
            float w = sW[wv][i][h];
            den += w;
            ushort4 u = *(const ushort4*)(featb + (size_t)s * 128 + f0);
            ax += w * bf2f(u.x);
            ay += w * bf2f(u.y);
            az += w * bf2f(u.z);
            aw += w * bf2f(u.w);
        }
    }

    // merge the two edge parities (each lane keeps its feature quad)
    ax += __shfl_down(ax, 32);
    ay += __shfl_down(ay, 32);
    az += __shfl_down(az, 32);
    aw += __shfl_down(aw, 32);
    den += __shfl_down(den, 32);

    if (lane < 32) {
        float scale = den > 0.f ? 1.f / den : 0.f;
        size_t o0 = (size_t)nd * 128 + f0;
        float4 o;
        o.x = ax * scale; o.y = ay * scale; o.z = az * scale; o.w = aw * scale;
        if (res) {
            float4 rv = *(const float4*)(res + o0);
            o.x += rv.x; o.y += rv.y; o.z += rv.z; o.w += rv.w;
        }
        o.x = fmaxf(o.x, 0.f);
        o.y = fmaxf(o.y, 0.f);
        o.z = fmaxf(o.z, 0.f);
        o.w = fmaxf(o.w, 0.f);
        *(float4*)(out + o0) = o;
    }
}

// ---------------------------------------------------------------------------
// Pull aggregation, H=1, C=16: wave per node, LDS staging, 8 edge-groups of
// 8 lanes; lane owns a feature pair (ushort2). No shuffles in the loop.
// ---------------------------------------------------------------------------
__global__ __launch_bounds__(256) void gat_agg16(const int* __restrict__ rowptr,
                                                 const int* __restrict__ deg,
                                                 const int* __restrict__ sorted_src,
                                                 const float* __restrict__ el,
                                                 const float* __restrict__ er,
                                                 const unsigned short* __restrict__ feat2b,
                                                 const float* __restrict__ res,
                                                 float* __restrict__ out) {
    __shared__ int   sS[4][64];
    __shared__ float sW[4][64];

    const int wv   = threadIdx.x >> 6;
    const int lane = threadIdx.x & 63;
    const int nd   = blockIdx.x * 4 + wv;
    const int g    = lane >> 3;          // edge group 0..7
    const int f2   = (lane & 7) * 2;     // feature pair base

    const int dg = deg[nd];
    const int r0 = rowptr[nd];
    const float erd = er[nd];

    float ax = 0.f, ay = 0.f, den = 0.f;

    for (int base = 0; base < dg; base += 64) {
        int m = dg - base; if (m > 64) m = 64;
        if (lane < m) {
            int s = sorted_src[r0 + base + lane];
            sS[wv][lane] = s;
            float v = el[s] + erd;
            v = v > 0.f ? v : NEG_SLOPE * v;
            sW[wv][lane] = __expf(v);
        }
        for (int i = g; i < m; i += 8) {
            int s   = sS[wv][i];
            float w = sW[wv][i];
            den += w;
            ushort2 u = *(const ushort2*)(feat2b + (size_t)s * 16 + f2);
            ax += w * bf2f(u.x);
            ay += w * bf2f(u.y);
        }
    }

    ax += __shfl_down(ax, 32); ay += __shfl_down(ay, 32); den += __shfl_down(den, 32);
    ax += __shfl_down(ax, 16); ay += __shfl_down(ay, 16); den += __shfl_down(den, 16);
    ax += __shfl_down(ax, 8);  ay += __shfl_down(ay, 8);  den += __shfl_down(den, 8);

    if (lane < 8) {
        float scale = den > 0.f ? 1.f / den : 0.f;
        size_t o0 = (size_t)nd * 16 + f2;
        float2 o;
        o.x = ax * scale + res[o0];
        o.y = ay * scale + res[o0 + 1];
        *(float2*)(out + o0) = o;
    }
}

// ---------------------------------------------------------------------------
extern "C" void kernel_launch(void* const* d_in, const int* in_sizes, int n_in,
                              void* d_out, int out_size, void* d_ws, size_t ws_size,
                              hipStream_t stream) {
    const float* inputs = (const float*)d_in[0];
    const int*   src    = (const int*)d_in[1];
    const int*   dst    = (const int*)d_in[2];
    const float* W0     = (const float*)d_in[3];
    const float* al0    = (const float*)d_in[4];
    const float* ar0    = (const float*)d_in[5];
    const float* W1     = (const float*)d_in[6];
    const float* al1    = (const float*)d_in[7];
    const float* ar1    = (const float*)d_in[8];
    const float* W2     = (const float*)d_in[9];
    const float* al2    = (const float*)d_in[10];
    const float* ar2    = (const float*)d_in[11];
    const float* resW2  = (const float*)d_in[12];
    float* out = (float*)d_out;

    const size_t NF = (size_t)N_NODES * 128;
    float* ws   = (float*)d_ws;
    float* hbuf = ws;                                  // N*128 f32
    float* el   = ws + NF;                             // N*4
    float* er   = el + (size_t)N_NODES * 4;            // N*4
    float* res2 = er + (size_t)N_NODES * 4;            // N*16
    unsigned short* featb  = (unsigned short*)(res2 + (size_t)N_NODES * 16);  // N*128
    unsigned short* feat2b = featb + NF;                                      // N*16
    int* iws = (int*)(feat2b + (size_t)N_NODES * 16);
    uint2* pe        = (uint2*)iws;                    // E uint2
    int* deg         = iws + 2 * N_EDGES;              // N
    int* rowptr      = deg + N_NODES;                  // N
    int* sorted_src  = rowptr + N_NODES;               // E
    int* bcount      = sorted_src + N_EDGES;           // 512
    int* bbase       = bcount + NBUCK;                 // 512
    int* bcursor     = bbase + NBUCK;                  // 512

    dim3 blk(256);
    int gemmGrid = (N_NODES + 63) / 64;
    int pGrid    = (N_EDGES + PCHUNK - 1) / PCHUNK;    // 391
    int bGrid    = (N_NODES + 255) / 256;              // 391
    int aggGrid  = N_NODES / 4;                        // 25000

    // ---------------- CSR build (locality-aware counting sort) -------------
    hipMemsetAsync(bcount, 0, NBUCK * sizeof(int), stream);
    bucket_count_k<<<pGrid, blk, 0, stream>>>(dst, bcount, N_EDGES);
    scan512<<<1, NBUCK, 0, stream>>>(bcount, bbase, bcursor);
    partition_k<<<pGrid, dim3(512), 0, stream>>>(src, dst, bcursor, pe, N_EDGES);
    bucket_finalize<<<bGrid, blk, 0, stream>>>(pe, bbase, rowptr, deg, sorted_src, N_EDGES);

    // ---------------- layer 0 ----------------
    gemm128_fused<<<gemmGrid, blk, 0, stream>>>(inputs, W0, al0, ar0, featb, el, er, N_NODES);
    gat_agg128<<<aggGrid, blk, 0, stream>>>(rowptr, deg, sorted_src, el, er, featb,
                                            nullptr, hbuf);

    // ---------------- layer 1 ----------------
    gemm128_fused<<<gemmGrid, blk, 0, stream>>>(hbuf, W1, al1, ar1, featb, el, er, N_NODES);
    gat_agg128<<<aggGrid, blk, 0, stream>>>(rowptr, deg, sorted_src, el, er, featb,
                                            hbuf, hbuf);

    // ---------------- layer 2 ----------------
    gemm16_dual<<<gemmGrid, blk, 0, stream>>>(hbuf, W2, resW2, al2, ar2, feat2b, res2,
                                              el, er, N_NODES);
    gat_agg16<<<aggGrid, blk, 0, stream>>>(rowptr, deg, sorted_src, el, er, feat2b,
                                           res2, out);
}

// Round 9
// 432.739 us; speedup vs baseline: 1.1549x; 1.1549x over previous
//
#include <hip/hip_runtime.h>

#define N_NODES 100000
#define N_EDGES 1600000
#define IN_F    128
#define NEG_SLOPE 0.2f
#define NBUCK   512                 // scan width; active buckets = 391
#define PCHUNK  4096                // edges per partition block

typedef __attribute__((ext_vector_type(8))) short bf16x8;
typedef __attribute__((ext_vector_type(4))) float f32x4;

__device__ __forceinline__ float bf2f(unsigned short u) {
    return __uint_as_float(((unsigned int)u) << 16);
}

// f32 -> bf16 round-to-nearest-even
__device__ __forceinline__ unsigned short f2bf(float f) {
    unsigned int u = __float_as_uint(f);
    u += 0x7FFFu + ((u >> 16) & 1u);
    return (unsigned short)(u >> 16);
}

// ---------------------------------------------------------------------------
// Weight pack: W (128x128 f32, row-major k x n) -> bf16 fragment order
// Wp[((nt*4+kt)*64+lane)*8+j] = W[kt*32+(lane>>4)*8+j][nt*16+(lane&15)]
// so a wave's B-frag load for tile (nt,kt) is 1KB contiguous.
// ---------------------------------------------------------------------------
__global__ __launch_bounds__(256) void pack_w128(const float* __restrict__ W,
                                                 unsigned short* __restrict__ Wp) {
    int idx = blockIdx.x * 256 + threadIdx.x;        // < 16384
    int j  = idx & 7;
    int l  = (idx >> 3) & 63;
    int kt = (idx >> 9) & 3;
    int nt = idx >> 11;
    int k  = kt * 32 + (l >> 4) * 8 + j;
    int n  = nt * 16 + (l & 15);
    Wp[idx] = f2bf(W[k * 128 + n]);
}

// Pack [W2 | resW2] (128x16 each) as one 128x32 matrix, same fragment order.
__global__ __launch_bounds__(256) void pack_w32(const float* __restrict__ W2,
                                                const float* __restrict__ rW2,
                                                unsigned short* __restrict__ Wp) {
    int idx = blockIdx.x * 256 + threadIdx.x;        // < 8192
    int j  = idx & 7;
    int l  = (idx >> 3) & 63;
    int kt = (idx >> 9) & 3;
    int nt = idx >> 11;                              // 0..1
    int k  = kt * 32 + (l >> 4) * 8 + j;
    int n  = nt * 16 + (l & 15);
    float v = (n < 16) ? W2[k * 16 + n] : rW2[k * 16 + (n - 16)];
    Wp[idx] = f2bf(v);
}

// ---------------------------------------------------------------------------
// MFMA GEMM hidden layers: featb(bf16) = A(f32, nrows x 128) @ W (packed bf16),
// el/er per (node,head) computed from C-fragments in the epilogue.
// Block: 256 thr = 4 waves; wave w owns rows [blk*64 + w*16, +16).
// A staged f32->bf16 in LDS, row stride 136 (pad 8) for conflict-free frags.
// ---------------------------------------------------------------------------
__global__ __launch_bounds__(256) void gemm128_mfma(const float* __restrict__ A,
                                                    const unsigned short* __restrict__ Wp,
                                                    const float* __restrict__ al,
                                                    const float* __restrict__ ar,
                                                    unsigned short* __restrict__ featb,
                                                    float* __restrict__ el,
                                                    float* __restrict__ er,
                                                    int nrows) {
    __shared__ unsigned short sA[64][136];
    const int t    = threadIdx.x;
    const int row0 = blockIdx.x * 64;

    // stage 64x128 f32 -> bf16 LDS (8 float4 per thread)
#pragma unroll
    for (int i = 0; i < 8; ++i) {
        int e  = (i * 256 + t) * 4;
        int r  = e >> 7;
        int c  = e & 127;
        float4 v = make_float4(0.f, 0.f, 0.f, 0.f);
        int gr = row0 + r;
        if (gr < nrows) v = *(const float4*)(A + (size_t)gr * IN_F + c);
        ushort4 u;
        u.x = f2bf(v.x); u.y = f2bf(v.y); u.z = f2bf(v.z); u.w = f2bf(v.w);
        *(ushort4*)(&sA[r][c]) = u;
    }
    __syncthreads();

    const int wv   = t >> 6;
    const int lane = t & 63;
    const int q    = lane >> 4;
    const int m    = lane & 15;
    const int m0   = wv * 16;

    f32x4 acc[8];
#pragma unroll
    for (int nt = 0; nt < 8; ++nt) acc[nt] = (f32x4){0.f, 0.f, 0.f, 0.f};

#pragma unroll
    for (int kt = 0; kt < 4; ++kt) {
        bf16x8 afr = *(const bf16x8*)(&sA[m0 + m][kt * 32 + q * 8]);
#pragma unroll
        for (int nt = 0; nt < 8; ++nt) {
            bf16x8 bfr = *(const bf16x8*)(Wp + ((size_t)(nt * 4 + kt) * 64 + lane) * 8);
            acc[nt] = __builtin_amdgcn_mfma_f32_16x16x32_bf16(afr, bfr, acc[nt], 0, 0, 0);
        }
    }

    // epilogue: bf16 feat store + el/er partials (row = row0+m0+q*4+reg, col = nt*16+m)
    float pel[16], per[16];
#pragma unroll
    for (int i = 0; i < 16; ++i) { pel[i] = 0.f; per[i] = 0.f; }

#pragma unroll
    for (int nt = 0; nt < 8; ++nt) {
        const int col = nt * 16 + m;
        const float alv = al[col];
        const float arv = ar[col];
        const int h = nt >> 1;
#pragma unroll
        for (int reg = 0; reg < 4; ++reg) {
            int row = row0 + m0 + q * 4 + reg;
            float a = acc[nt][reg];
            if (row < nrows) featb[(size_t)row * 128 + col] = f2bf(a);
            pel[reg * 4 + h] += a * alv;
            per[reg * 4 + h] += a * arv;
        }
    }

    // reduce across the 16 lanes of each quad (contiguous lanes q*16..q*16+15)
#pragma unroll
    for (int s = 8; s > 0; s >>= 1) {
#pragma unroll
        for (int i = 0; i < 16; ++i) {
            pel[i] += __shfl_down(pel[i], s);
            per[i] += __shfl_down(per[i], s);
        }
    }
    if (m == 0) {
#pragma unroll
        for (int reg = 0; reg < 4; ++reg) {
            int row = row0 + m0 + q * 4 + reg;
            if (row < nrows) {
#pragma unroll
                for (int h = 0; h < 4; ++h) {
                    el[row * 4 + h] = pel[reg * 4 + h];
                    er[row * 4 + h] = per[reg * 4 + h];
                }
            }
        }
    }
}

// ---------------------------------------------------------------------------
// MFMA dual GEMM layer 2: [feat2b(bf16) | res2(f32)] = A @ [W2|resW2] (packed),
// el/er (1 head) from the nt=0 fragments.
// ---------------------------------------------------------------------------
__global__ __launch_bounds__(256) void gemm16_mfma(const float* __restrict__ A,
                                                   const unsigned short* __restrict__ Wp,
                                                   const float* __restrict__ al,
                                                   const float* __restrict__ ar,
                                                   unsigned short* __restrict__ feat2b,
                                                   float* __restrict__ res2,
                                                   float* __restrict__ el,
                                                   float* __restrict__ er,
                                                   int nrows) {
    __shared__ unsigned short sA[64][136];
    const int t    = threadIdx.x;
    const int row0 = blockIdx.x * 64;

#pragma unroll
    for (int i = 0; i < 8; ++i) {
        int e  = (i * 256 + t) * 4;
        int r  = e >> 7;
        int c  = e & 127;
        float4 v = make_float4(0.f, 0.f, 0.f, 0.f);
        int gr = row0 + r;
        if (gr < nrows) v = *(const float4*)(A + (size_t)gr * IN_F + c);
        ushort4 u;
        u.x = f2bf(v.x); u.y = f2bf(v.y); u.z = f2bf(v.z); u.w = f2bf(v.w);
        *(ushort4*)(&sA[r][c]) = u;
    }
    __syncthreads();

    const int wv   = t >> 6;
    const int lane = t & 63;
    const int q    = lane >> 4;
    const int m    = lane & 15;
    const int m0   = wv * 16;

    f32x4 acc0 = (f32x4){0.f, 0.f, 0.f, 0.f};
    f32x4 acc1 = (f32x4){0.f, 0.f, 0.f, 0.f};

#pragma unroll
    for (int kt = 0; kt < 4; ++kt) {
        bf16x8 afr = *(const bf16x8*)(&sA[m0 + m][kt * 32 + q * 8]);
        bf16x8 b0  = *(const bf16x8*)(Wp + ((size_t)(0 * 4 + kt) * 64 + lane) * 8);
        bf16x8 b1  = *(const bf16x8*)(Wp + ((size_t)(1 * 4 + kt) * 64 + lane) * 8);
        acc0 = __builtin_amdgcn_mfma_f32_16x16x32_bf16(afr, b0, acc0, 0, 0, 0);
        acc1 = __builtin_amdgcn_mfma_f32_16x16x32_bf16(afr, b1, acc1, 0, 0, 0);
    }

    float pel[4], per[4];
    const float alv = al[m];
    const float arv = ar[m];
#pragma unroll
    for (int reg = 0; reg < 4; ++reg) {
        int row = row0 + m0 + q * 4 + reg;
        float a = acc0[reg];
        if (row < nrows) {
            feat2b[(size_t)row * 16 + m] = f2bf(a);
            res2[(size_t)row * 16 + m]   = acc1[reg];
        }
        pel[reg] = a * alv;
        per[reg] = a * arv;
    }
#pragma unroll
    for (int s = 8; s > 0; s >>= 1) {
#pragma unroll
        for (int reg = 0; reg < 4; ++reg) {
            pel[reg] += __shfl_down(pel[reg], s);
            per[reg] += __shfl_down(per[reg], s);
        }
    }
    if (m == 0) {
#pragma unroll
        for (int reg = 0; reg < 4; ++reg) {
            int row = row0 + m0 + q * 4 + reg;
            if (row < nrows) { el[row] = pel[reg]; er[row] = per[reg]; }
        }
    }
}

// ---------------------------------------------------------------------------
// CSR build, locality-aware. Bucket = dst>>8 (256-node windows, 391 active).
// ---------------------------------------------------------------------------
__global__ __launch_bounds__(256) void bucket_count_k(const int* __restrict__ dst,
                                                      int* __restrict__ bcount, int nE) {
    __shared__ int hist[NBUCK];
    const int t = threadIdx.x;
    hist[t] = 0; hist[t + 256] = 0;
    __syncthreads();
    const int start = blockIdx.x * PCHUNK;
#pragma unroll
    for (int j = 0; j < PCHUNK / 256; ++j) {
        int e = start + j * 256 + t;
        if (e < nE) atomicAdd(&hist[dst[e] >> 8], 1);
    }
    __syncthreads();
    if (hist[t])       atomicAdd(&bcount[t],       hist[t]);
    if (hist[t + 256]) atomicAdd(&bcount[t + 256], hist[t + 256]);
}

__global__ __launch_bounds__(NBUCK) void scan512(const int* __restrict__ bcount,
                                                 int* __restrict__ bbase,
                                                 int* __restrict__ bcursor) {
    __shared__ int s[NBUCK];
    const int t = threadIdx.x;
    int v = bcount[t];
    s[t] = v;
    __syncthreads();
#pragma unroll
    for (int off = 1; off < NBUCK; off <<= 1) {
        int x = (t >= off) ? s[t - off] : 0;
        __syncthreads();
        s[t] += x;
        __syncthreads();
    }
    int excl = s[t] - v;
    bbase[t]   = excl;
    bcursor[t] = excl;
}

__global__ __launch_bounds__(512) void partition_k(const int* __restrict__ src,
                                                   const int* __restrict__ dst,
                                                   int* __restrict__ bcursor,
                                                   uint2* __restrict__ pe, int nE) {
    __shared__ int   hist[NBUCK];
    __shared__ int   lstart[NBUCK];
    __shared__ int   gbase[NBUCK];
    __shared__ int   curB[NBUCK];
    __shared__ uint2 reorder[PCHUNK];

    const int t = threadIdx.x;
    const int start = blockIdx.x * PCHUNK;
    const int m = min(PCHUNK, nE - start);

    hist[t] = 0;
    __syncthreads();

#pragma unroll
    for (int j = 0; j < PCHUNK / 512; ++j) {
        int e = start + j * 512 + t;
        if (e < nE) atomicAdd(&hist[dst[e] >> 8], 1);
    }
    __syncthreads();
    const int cnt = hist[t];

    __shared__ int s[NBUCK];
    s[t] = cnt;
    __syncthreads();
#pragma unroll
    for (int off = 1; off < NBUCK; off <<= 1) {
        int x = (t >= off) ? s[t - off] : 0;
        __syncthreads();
        s[t] += x;
        __syncthreads();
    }
    lstart[t] = s[t] - cnt;
    curB[t]   = s[t] - cnt;
    gbase[t] = cnt ? atomicAdd(&bcursor[t], cnt) : 0;
    __syncthreads();

#pragma unroll
    for (int j = 0; j < PCHUNK / 512; ++j) {
        int e = start + j * 512 + t;
        if (e < nE) {
            int d = dst[e];
            int pos = atomicAdd(&curB[d >> 8], 1);
            reorder[pos] = make_uint2((unsigned)src[e], (unsigned)d);
        }
    }
    __syncthreads();

    for (int i = t; i < m; i += 512) {
        uint2 ed = reorder[i];
        int b = (int)(ed.y >> 8);
        pe[gbase[b] + (i - lstart[b])] = ed;
    }
}

__global__ __launch_bounds__(256) void bucket_finalize(const uint2* __restrict__ pe,
                                                       const int* __restrict__ bbase,
                                                       int* __restrict__ rowptr,
                                                       int* __restrict__ deg,
                                                       int* __restrict__ sorted_src,
                                                       int nE) {
    __shared__ int deg_l[256];
    __shared__ int s[256];
    __shared__ int cur[256];

    const int b  = blockIdx.x;
    const int t  = threadIdx.x;
    const int base = bbase[b];
    const int endE = (b + 1 < NBUCK) ? bbase[b + 1] : nE;
    const int cnt  = endE - base;
    const int n    = b * 256 + t;

    deg_l[t] = 0;
    __syncthreads();
    for (int i = t; i < cnt; i += 256)
        atomicAdd(&deg_l[pe[base + i].y & 255u], 1);
    __syncthreads();

    const int dv = deg_l[t];
    s[t] = dv;
    __syncthreads();
#pragma unroll
    for (int off = 1; off < 256; off <<= 1) {
        int x = (t >= off) ? s[t - off] : 0;
        __syncthreads();
        s[t] += x;
        __syncthreads();
    }
    const int off_l = s[t] - dv;
    if (n < N_NODES) {
        rowptr[n] = base + off_l;
        deg[n]    = dv;
    }
    cur[t] = off_l;
    __syncthreads();

    for (int i = t; i < cnt; i += 256) {
        uint2 ed = pe[base + i];
        int pos = atomicAdd(&cur[ed.y & 255u], 1);
        sorted_src[base + pos] = (int)ed.x;
    }
}

// ---------------------------------------------------------------------------
// Pull aggregation, H=4, D=32 (128 feats), bf16 gathers, wave per node.
// (round-7 version: 83 us measured; the 2-edge/iter variant regressed)
// ---------------------------------------------------------------------------
__global__ __launch_bounds__(256) void gat_agg128(const int* __restrict__ rowptr,
                                                  const int* __restrict__ deg,
                                                  const int* __restrict__ sorted_src,
                                                  const float* __restrict__ el,
                                                  const float* __restrict__ er,
                                                  const unsigned short* __restrict__ featb,
                                                  const float* __restrict__ res,
                                                  float* __restrict__ out) {
    __shared__ int   sS[4][64];
    __shared__ float sW[4][64][4];

    const int wv   = threadIdx.x >> 6;
    const int lane = threadIdx.x & 63;
    const int nd   = blockIdx.x * 4 + wv;

    const int dg = deg[nd];
    const int r0 = rowptr[nd];
    const int h  = lane >> 4;
    const float4 er4 = *(const float4*)(er + nd * 4);

    float den = 0.f;
    float ax = 0.f, ay = 0.f;

    for (int base = 0; base < dg; base += 64) {
        int m = dg - base; if (m > 64) m = 64;
        if (lane < m) {
            int s = sorted_src[r0 + base + lane];
            sS[wv][lane] = s;
            float4 e4 = *(const float4*)(el + s * 4);
            float4 w;
            float v;
            v = e4.x + er4.x; v = v > 0.f ? v : NEG_SLOPE * v; w.x = __expf(v);
            v = e4.y + er4.y; v = v > 0.f ? v : NEG_SLOPE * v; w.y = __expf(v);
            v = e4.z + er4.z; v = v > 0.f ? v : NEG_SLOPE * v; w.z = __expf(v);
            v = e4.w + er4.w; v = v > 0.f ? v : NEG_SLOPE * v; w.w = __expf(v);
            *(float4*)(&sW[wv][lane][0]) = w;
        }
        // wave-synchronous: same wave wrote LDS
        for (int i = 0; i < m; ++i) {
            int s   = sS[wv][i];
            float w = sW[wv][i][h];
            den += w;
            ushort2 u = *(const ushort2*)(featb + (size_t)s * 128 + lane * 2);
            ax += w * bf2f(u.x);
            ay += w * bf2f(u.y);
        }
    }

    float scale = den > 0.f ? 1.f / den : 0.f;
    float ox = ax * scale, oy = ay * scale;
    size_t o0 = (size_t)nd * 128 + lane * 2;
    if (res) { ox += res[o0]; oy += res[o0 + 1]; }
    ox = fmaxf(ox, 0.f);
    oy = fmaxf(oy, 0.f);
    *(float2*)(out + o0) = make_float2(ox, oy);
}

// ---------------------------------------------------------------------------
// Pull aggregation, H=1, C=16: wave per node, LDS staging, 8 edge-groups of
// 8 lanes; lane owns a feature pair (ushort2). No shuffles in the loop.
// ---------------------------------------------------------------------------
__global__ __launch_bounds__(256) void gat_agg16(const int* __restrict__ rowptr,
                                                 const int* __restrict__ deg,
                                                 const int* __restrict__ sorted_src,
                                                 const float* __restrict__ el,
                                                 const float* __restrict__ er,
                                                 const unsigned short* __restrict__ feat2b,
                                                 const float* __restrict__ res,
                                                 float* __restrict__ out) {
    __shared__ int   sS[4][64];
    __shared__ float sW[4][64];

    const int wv   = threadIdx.x >> 6;
    const int lane = threadIdx.x & 63;
    const int nd   = blockIdx.x * 4 + wv;
    const int g    = lane >> 3;          // edge group 0..7
    const int f2   = (lane & 7) * 2;     // feature pair base

    const int dg = deg[nd];
    const int r0 = rowptr[nd];
    const float erd = er[nd];

    float ax = 0.f, ay = 0.f, den = 0.f;

    for (int base = 0; base < dg; base += 64) {
        int m = dg - base; if (m > 64) m = 64;
        if (lane < m) {
            int s = sorted_src[r0 + base + lane];
            sS[wv][lane] = s;
            float v = el[s] + erd;
            v = v > 0.f ? v : NEG_SLOPE * v;
            sW[wv][lane] = __expf(v);
        }
        for (int i = g; i < m; i += 8) {
            int s   = sS[wv][i];
            float w = sW[wv][i];
            den += w;
            ushort2 u = *(const ushort2*)(feat2b + (size_t)s * 16 + f2);
            ax += w * bf2f(u.x);
            ay += w * bf2f(u.y);
        }
    }

    ax += __shfl_down(ax, 32); ay += __shfl_down(ay, 32); den += __shfl_down(den, 32);
    ax += __shfl_down(ax, 16); ay += __shfl_down(ay, 16); den += __shfl_down(den, 16);
    ax += __shfl_down(ax, 8);  ay += __shfl_down(ay, 8);  den += __shfl_down(den, 8);

    if (lane < 8) {
        float scale = den > 0.f ? 1.f / den : 0.f;
        size_t o0 = (size_t)nd * 16 + f2;
        float2 o;
        o.x = ax * scale + res[o0];
        o.y = ay * scale + res[o0 + 1];
        *(float2*)(out + o0) = o;
    }
}

// ---------------------------------------------------------------------------
extern "C" void kernel_launch(void* const* d_in, const int* in_sizes, int n_in,
                              void* d_out, int out_size, void* d_ws, size_t ws_size,
                              hipStream_t stream) {
    const float* inputs = (const float*)d_in[0];
    const int*   src    = (const int*)d_in[1];
    const int*   dst    = (const int*)d_in[2];
    const float* W0     = (const float*)d_in[3];
    const float* al0    = (const float*)d_in[4];
    const float* ar0    = (const float*)d_in[5];
    const float* W1     = (const float*)d_in[6];
    const float* al1    = (const float*)d_in[7];
    const float* ar1    = (const float*)d_in[8];
    const float* W2     = (const float*)d_in[9];
    const float* al2    = (const float*)d_in[10];
    const float* ar2    = (const float*)d_in[11];
    const float* resW2  = (const float*)d_in[12];
    float* out = (float*)d_out;

    const size_t NF = (size_t)N_NODES * 128;
    float* ws   = (float*)d_ws;
    float* hbuf = ws;                                  // N*128 f32
    float* el   = ws + NF;                             // N*4
    float* er   = el + (size_t)N_NODES * 4;            // N*4
    float* res2 = er + (size_t)N_NODES * 4;            // N*16
    unsigned short* featb  = (unsigned short*)(res2 + (size_t)N_NODES * 16);  // N*128
    unsigned short* feat2b = featb + NF;                                      // N*16
    unsigned short* W0p    = feat2b + (size_t)N_NODES * 16;  // 16384
    unsigned short* W1p    = W0p + 16384;                    // 16384
    unsigned short* W2p    = W1p + 16384;                    // 8192
    int* iws = (int*)(W2p + 8192);
    uint2* pe        = (uint2*)iws;                    // E uint2
    int* deg         = iws + 2 * N_EDGES;              // N
    int* rowptr      = deg + N_NODES;                  // N
    int* sorted_src  = rowptr + N_NODES;               // E
    int* bcount      = sorted_src + N_EDGES;           // 512
    int* bbase       = bcount + NBUCK;                 // 512
    int* bcursor     = bbase + NBUCK;                  // 512

    dim3 blk(256);
    int gemmGrid = (N_NODES + 63) / 64;
    int pGrid    = (N_EDGES + PCHUNK - 1) / PCHUNK;    // 391
    int bGrid    = (N_NODES + 255) / 256;              // 391
    int aggGrid  = N_NODES / 4;                        // 25000

    // ---------------- CSR build (locality-aware counting sort) -------------
    hipMemsetAsync(bcount, 0, NBUCK * sizeof(int), stream);
    bucket_count_k<<<pGrid, blk, 0, stream>>>(dst, bcount, N_EDGES);
    scan512<<<1, NBUCK, 0, stream>>>(bcount, bbase, bcursor);
    partition_k<<<pGrid, dim3(512), 0, stream>>>(src, dst, bcursor, pe, N_EDGES);
    bucket_finalize<<<bGrid, blk, 0, stream>>>(pe, bbase, rowptr, deg, sorted_src, N_EDGES);

    // ---------------- weight packing ----------------
    pack_w128<<<64, blk, 0, stream>>>(W0, W0p);
    pack_w128<<<64, blk, 0, stream>>>(W1, W1p);
    pack_w32<<<32, blk, 0, stream>>>(W2, resW2, W2p);

    // ---------------- layer 0 ----------------
    gemm128_mfma<<<gemmGrid, blk, 0, stream>>>(inputs, W0p, al0, ar0, featb, el, er, N_NODES);
    gat_agg128<<<aggGrid, blk, 0, stream>>>(rowptr, deg, sorted_src, el, er, featb,
                                            nullptr, hbuf);

    // ---------------- layer 1 ----------------
    gemm128_mfma<<<gemmGrid, blk, 0, stream>>>(hbuf, W1p, al1, ar1, featb, el, er, N_NODES);
    gat_agg128<<<aggGrid, blk, 0, stream>>>(rowptr, deg, sorted_src, el, er, featb,
                                            hbuf, hbuf);

    // ---------------- layer 2 ----------------
    gemm16_mfma<<<gemmGrid, blk, 0, stream>>>(hbuf, W2p, al2, ar2, feat2b, res2,
                                              el, er, N_NODES);
    gat_agg16<<<aggGrid, blk, 0, stream>>>(rowptr, deg, sorted_src, el, er, feat2b,
                                           res2, out);
}

// Round 10
// 412.699 us; speedup vs baseline: 1.2110x; 1.0486x over previous
//
#include <hip/hip_runtime.h>

#define N_NODES 100000
#define N_EDGES 1600000
#define IN_F    128
#define NEG_SLOPE 0.2f
#define NBUCK   512                 // scan width; active buckets = 391
#define PCHUNK  4096                // edges per partition block

typedef __attribute__((ext_vector_type(8))) short bf16x8;
typedef __attribute__((ext_vector_type(4))) float f32x4;

__device__ __forceinline__ float bf2f(unsigned short u) {
    return __uint_as_float(((unsigned int)u) << 16);
}

// f32 -> bf16 round-to-nearest-even
__device__ __forceinline__ unsigned short f2bf(float f) {
    unsigned int u = __float_as_uint(f);
    u += 0x7FFFu + ((u >> 16) & 1u);
    return (unsigned short)(u >> 16);
}

// ---------------------------------------------------------------------------
// Weight pack (all three matrices in one launch), bf16 fragment order:
// Wp[((nt*4+kt)*64+lane)*8+j] = W[kt*32+(lane>>4)*8+j][nt*16+(lane&15)]
// ---------------------------------------------------------------------------
__global__ __launch_bounds__(256) void pack_all(const float* __restrict__ W0,
                                                const float* __restrict__ W1,
                                                const float* __restrict__ W2,
                                                const float* __restrict__ rW2,
                                                unsigned short* __restrict__ W0p,
                                                unsigned short* __restrict__ W1p,
                                                unsigned short* __restrict__ W2p) {
    int gid = blockIdx.x * 256 + threadIdx.x;        // < 40960
    const float* W;
    unsigned short* Wp;
    int idx, ncols;
    if (gid < 16384)      { W = W0; Wp = W0p; idx = gid;          ncols = 128; }
    else if (gid < 32768) { W = W1; Wp = W1p; idx = gid - 16384;  ncols = 128; }
    else                  { W = W2; Wp = W2p; idx = gid - 32768;  ncols = 32;  }
    int j  = idx & 7;
    int l  = (idx >> 3) & 63;
    int kt = (idx >> 9) & 3;
    int nt = idx >> 11;
    int k  = kt * 32 + (l >> 4) * 8 + j;
    int n  = nt * 16 + (l & 15);
    float v;
    if (ncols == 128) v = W[k * 128 + n];
    else              v = (n < 16) ? W[k * 16 + n] : rW2[k * 16 + (n - 16)];
    Wp[idx] = f2bf(v);
}

// ---------------------------------------------------------------------------
// MFMA GEMM, f32 A (layer 0): featb(bf16) = A @ W, el/er fused. No LDS, no
// barrier: each lane loads its A-fragment directly (4 lanes/row fill a line).
// ---------------------------------------------------------------------------
__global__ __launch_bounds__(256) void gemm128_mfma_f32(const float* __restrict__ A,
                                                        const unsigned short* __restrict__ Wp,
                                                        const float* __restrict__ al,
                                                        const float* __restrict__ ar,
                                                        unsigned short* __restrict__ featb,
                                                        float* __restrict__ el,
                                                        float* __restrict__ er,
                                                        int nrows) {
    const int t    = threadIdx.x;
    const int wv   = t >> 6;
    const int lane = t & 63;
    const int q    = lane >> 4;
    const int m    = lane & 15;
    const int rb   = blockIdx.x * 64 + wv * 16;      // wave's row base
    const int arow = rb + m;
    const bool rok = arow < nrows;
    const float* Ar = A + (size_t)arow * IN_F;

    f32x4 acc[8];
#pragma unroll
    for (int nt = 0; nt < 8; ++nt) acc[nt] = (f32x4){0.f, 0.f, 0.f, 0.f};

#pragma unroll
    for (int kt = 0; kt < 4; ++kt) {
        bf16x8 afr = (bf16x8){0, 0, 0, 0, 0, 0, 0, 0};
        if (rok) {
            float4 v0 = *(const float4*)(Ar + kt * 32 + q * 8);
            float4 v1 = *(const float4*)(Ar + kt * 32 + q * 8 + 4);
            afr[0] = (short)f2bf(v0.x); afr[1] = (short)f2bf(v0.y);
            afr[2] = (short)f2bf(v0.z); afr[3] = (short)f2bf(v0.w);
            afr[4] = (short)f2bf(v1.x); afr[5] = (short)f2bf(v1.y);
            afr[6] = (short)f2bf(v1.z); afr[7] = (short)f2bf(v1.w);
        }
#pragma unroll
        for (int nt = 0; nt < 8; ++nt) {
            bf16x8 bfr = *(const bf16x8*)(Wp + ((size_t)(nt * 4 + kt) * 64 + lane) * 8);
            acc[nt] = __builtin_amdgcn_mfma_f32_16x16x32_bf16(afr, bfr, acc[nt], 0, 0, 0);
        }
    }

    float pel[16], per[16];
#pragma unroll
    for (int i = 0; i < 16; ++i) { pel[i] = 0.f; per[i] = 0.f; }

#pragma unroll
    for (int nt = 0; nt < 8; ++nt) {
        const int col = nt * 16 + m;
        const float alv = al[col];
        const float arv = ar[col];
        const int h = nt >> 1;
#pragma unroll
        for (int reg = 0; reg < 4; ++reg) {
            int row = rb + q * 4 + reg;
            float a = acc[nt][reg];
            if (row < nrows) featb[(size_t)row * 128 + col] = f2bf(a);
            pel[reg * 4 + h] += a * alv;
            per[reg * 4 + h] += a * arv;
        }
    }
#pragma unroll
    for (int s = 8; s > 0; s >>= 1) {
#pragma unroll
        for (int i = 0; i < 16; ++i) {
            pel[i] += __shfl_down(pel[i], s);
            per[i] += __shfl_down(per[i], s);
        }
    }
    if (m == 0) {
#pragma unroll
        for (int reg = 0; reg < 4; ++reg) {
            int row = rb + q * 4 + reg;
            if (row < nrows) {
#pragma unroll
                for (int h = 0; h < 4; ++h) {
                    el[row * 4 + h] = pel[reg * 4 + h];
                    er[row * 4 + h] = per[reg * 4 + h];
                }
            }
        }
    }
}

// ---------------------------------------------------------------------------
// MFMA GEMM, bf16 A (layer 1): same as above but A-frag is one 16B load.
// ---------------------------------------------------------------------------
__global__ __launch_bounds__(256) void gemm128_mfma_bf16(const unsigned short* __restrict__ Ab,
                                                         const unsigned short* __restrict__ Wp,
                                                         const float* __restrict__ al,
                                                         const float* __restrict__ ar,
                                                         unsigned short* __restrict__ featb,
                                                         float* __restrict__ el,
                                                         float* __restrict__ er,
                                                         int nrows) {
    const int t    = threadIdx.x;
    const int wv   = t >> 6;
    const int lane = t & 63;
    const int q    = lane >> 4;
    const int m    = lane & 15;
    const int rb   = blockIdx.x * 64 + wv * 16;
    const int arow = rb + m;
    const bool rok = arow < nrows;
    const unsigned short* Ar = Ab + (size_t)arow * IN_F;

    f32x4 acc[8];
#pragma unroll
    for (int nt = 0; nt < 8; ++nt) acc[nt] = (f32x4){0.f, 0.f, 0.f, 0.f};

#pragma unroll
    for (int kt = 0; kt < 4; ++kt) {
        bf16x8 afr = (bf16x8){0, 0, 0, 0, 0, 0, 0, 0};
        if (rok) afr = *(const bf16x8*)(Ar + kt * 32 + q * 8);
#pragma unroll
        for (int nt = 0; nt < 8; ++nt) {
            bf16x8 bfr = *(const bf16x8*)(Wp + ((size_t)(nt * 4 + kt) * 64 + lane) * 8);
            acc[nt] = __builtin_amdgcn_mfma_f32_16x16x32_bf16(afr, bfr, acc[nt], 0, 0, 0);
        }
    }

    float pel[16], per[16];
#pragma unroll
    for (int i = 0; i < 16; ++i) { pel[i] = 0.f; per[i] = 0.f; }

#pragma unroll
    for (int nt = 0; nt < 8; ++nt) {
        const int col = nt * 16 + m;
        const float alv = al[col];
        const float arv = ar[col];
        const int h = nt >> 1;
#pragma unroll
        for (int reg = 0; reg < 4; ++reg) {
            int row = rb + q * 4 + reg;
            float a = acc[nt][reg];
            if (row < nrows) featb[(size_t)row * 128 + col] = f2bf(a);
            pel[reg * 4 + h] += a * alv;
            per[reg * 4 + h] += a * arv;
        }
    }
#pragma unroll
    for (int s = 8; s > 0; s >>= 1) {
#pragma unroll
        for (int i = 0; i < 16; ++i) {
            pel[i] += __shfl_down(pel[i], s);
            per[i] += __shfl_down(per[i], s);
        }
    }
    if (m == 0) {
#pragma unroll
        for (int reg = 0; reg < 4; ++reg) {
            int row = rb + q * 4 + reg;
            if (row < nrows) {
#pragma unroll
                for (int h = 0; h < 4; ++h) {
                    el[row * 4 + h] = pel[reg * 4 + h];
                    er[row * 4 + h] = per[reg * 4 + h];
                }
            }
        }
    }
}

// ---------------------------------------------------------------------------
// MFMA dual GEMM layer 2 (bf16 A): [feat2b(bf16) | res2(f32)] = A @ [W2|resW2].
// ---------------------------------------------------------------------------
__global__ __launch_bounds__(256) void gemm16_mfma(const unsigned short* __restrict__ Ab,
                                                   const unsigned short* __restrict__ Wp,
                                                   const float* __restrict__ al,
                                                   const float* __restrict__ ar,
                                                   unsigned short* __restrict__ feat2b,
                                                   float* __restrict__ res2,
                                                   float* __restrict__ el,
                                                   float* __restrict__ er,
                                                   int nrows) {
    const int t    = threadIdx.x;
    const int wv   = t >> 6;
    const int lane = t & 63;
    const int q    = lane >> 4;
    const int m    = lane & 15;
    const int rb   = blockIdx.x * 64 + wv * 16;
    const int arow = rb + m;
    const bool rok = arow < nrows;
    const unsigned short* Ar = Ab + (size_t)arow * IN_F;

    f32x4 acc0 = (f32x4){0.f, 0.f, 0.f, 0.f};
    f32x4 acc1 = (f32x4){0.f, 0.f, 0.f, 0.f};

#pragma unroll
    for (int kt = 0; kt < 4; ++kt) {
        bf16x8 afr = (bf16x8){0, 0, 0, 0, 0, 0, 0, 0};
        if (rok) afr = *(const bf16x8*)(Ar + kt * 32 + q * 8);
        bf16x8 b0 = *(const bf16x8*)(Wp + ((size_t)(0 * 4 + kt) * 64 + lane) * 8);
        bf16x8 b1 = *(const bf16x8*)(Wp + ((size_t)(1 * 4 + kt) * 64 + lane) * 8);
        acc0 = __builtin_amdgcn_mfma_f32_16x16x32_bf16(afr, b0, acc0, 0, 0, 0);
        acc1 = __builtin_amdgcn_mfma_f32_16x16x32_bf16(afr, b1, acc1, 0, 0, 0);
    }

    float pel[4], per[4];
    const float alv = al[m];
    const float arv = ar[m];
#pragma unroll
    for (int reg = 0; reg < 4; ++reg) {
        int row = rb + q * 4 + reg;
        float a = acc0[reg];
        if (row < nrows) {
            feat2b[(size_t)row * 16 + m] = f2bf(a);
            res2[(size_t)row * 16 + m]   = acc1[reg];
        }
        pel[reg] = a * alv;
        per[reg] = a * arv;
    }
#pragma unroll
    for (int s = 8; s > 0; s >>= 1) {
#pragma unroll
        for (int reg = 0; reg < 4; ++reg) {
            pel[reg] += __shfl_down(pel[reg], s);
            per[reg] += __shfl_down(per[reg], s);
        }
    }
    if (m == 0) {
#pragma unroll
        for (int reg = 0; reg < 4; ++reg) {
            int row = rb + q * 4 + reg;
            if (row < nrows) { el[row] = pel[reg]; er[row] = per[reg]; }
        }
    }
}

// ---------------------------------------------------------------------------
// CSR build, locality-aware. Bucket = dst>>8. pe packed: (src<<8)|(dst&255).
// ---------------------------------------------------------------------------
__global__ __launch_bounds__(256) void bucket_count_k(const int* __restrict__ dst,
                                                      int* __restrict__ bcount, int nE) {
    __shared__ int hist[NBUCK];
    const int t = threadIdx.x;
    hist[t] = 0; hist[t + 256] = 0;
    __syncthreads();
    const int start = blockIdx.x * PCHUNK;
#pragma unroll
    for (int j = 0; j < PCHUNK / 256; ++j) {
        int e = start + j * 256 + t;
        if (e < nE) atomicAdd(&hist[dst[e] >> 8], 1);
    }
    __syncthreads();
    if (hist[t])       atomicAdd(&bcount[t],       hist[t]);
    if (hist[t + 256]) atomicAdd(&bcount[t + 256], hist[t + 256]);
}

__global__ __launch_bounds__(NBUCK) void scan512(const int* __restrict__ bcount,
                                                 int* __restrict__ bbase,
                                                 int* __restrict__ bcursor) {
    __shared__ int s[NBUCK];
    const int t = threadIdx.x;
    int v = bcount[t];
    s[t] = v;
    __syncthreads();
#pragma unroll
    for (int off = 1; off < NBUCK; off <<= 1) {
        int x = (t >= off) ? s[t - off] : 0;
        __syncthreads();
        s[t] += x;
        __syncthreads();
    }
    int excl = s[t] - v;
    bbase[t]   = excl;
    bcursor[t] = excl;
}

__global__ __launch_bounds__(512) void partition_k(const int* __restrict__ src,
                                                   const int* __restrict__ dst,
                                                   int* __restrict__ bcursor,
                                                   unsigned int* __restrict__ pe, int nE) {
    __shared__ int hist[NBUCK];
    __shared__ int lstart[NBUCK];
    __shared__ int gbase[NBUCK];
    __shared__ int curB[NBUCK];
    __shared__ unsigned int reorder[PCHUNK];

    const int t = threadIdx.x;
    const int start = blockIdx.x * PCHUNK;
    const int m = min(PCHUNK, nE - start);

    hist[t] = 0;
    __syncthreads();

#pragma unroll
    for (int j = 0; j < PCHUNK / 512; ++j) {
        int e = start + j * 512 + t;
        if (e < nE) atomicAdd(&hist[dst[e] >> 8], 1);
    }
    __syncthreads();
    const int cnt = hist[t];

    __shared__ int s[NBUCK];
    s[t] = cnt;
    __syncthreads();
#pragma unroll
    for (int off = 1; off < NBUCK; off <<= 1) {
        int x = (t >= off) ? s[t - off] : 0;
        __syncthreads();
        s[t] += x;
        __syncthreads();
    }
    lstart[t] = s[t] - cnt;
    curB[t]   = s[t] - cnt;
    gbase[t] = cnt ? atomicAdd(&bcursor[t], cnt) : 0;
    __syncthreads();

#pragma unroll
    for (int j = 0; j < PCHUNK / 512; ++j) {
        int e = start + j * 512 + t;
        if (e < nE) {
            int d = dst[e];
            int pos = atomicAdd(&curB[d >> 8], 1);
            reorder[pos] = ((unsigned)src[e] << 8) | ((unsigned)d & 255u);
        }
    }
    __syncthreads();

    for (int i = t; i < m; i += 512) {
        unsigned int ed = reorder[i];
        // bucket from position: find via lstart? cheaper: recompute from dst low bits
        // is impossible — carry bucket in high bits? src<<8 uses 25 bits; bucket
        // needs 9 bits -> doesn't fit. Use binary search over lstart instead? No:
        // iterate — position i belongs to bucket b where lstart[b] <= i < lstart[b+1].
        // Cheap alternative: store bucket in LDS per slot is extra 16KB. Use the
        // node-window trick: bucket = (node >> 8) where node = global dst; we kept
        // only dst&255. So reconstruct via lstart binary search (9 steps, LDS).
        int lo = 0, hi = NBUCK - 1;
        while (lo < hi) {
            int mid = (lo + hi + 1) >> 1;
            if (lstart[mid] <= i) lo = mid; else hi = mid - 1;
        }
        pe[gbase[lo] + (i - lstart[lo])] = ed;
    }
}

__global__ __launch_bounds__(256) void bucket_finalize(const unsigned int* __restrict__ pe,
                                                       const int* __restrict__ bbase,
                                                       int* __restrict__ rowptr,
                                                       int* __restrict__ deg,
                                                       int* __restrict__ sorted_src,
                                                       int nE) {
    __shared__ int deg_l[256];
    __shared__ int s[256];
    __shared__ int cur[256];

    const int b  = blockIdx.x;
    const int t  = threadIdx.x;
    const int base = bbase[b];
    const int endE = (b + 1 < NBUCK) ? bbase[b + 1] : nE;
    const int cnt  = endE - base;
    const int n    = b * 256 + t;

    deg_l[t] = 0;
    __syncthreads();
    for (int i = t; i < cnt; i += 256)
        atomicAdd(&deg_l[pe[base + i] & 255u], 1);
    __syncthreads();

    const int dv = deg_l[t];
    s[t] = dv;
    __syncthreads();
#pragma unroll
    for (int off = 1; off < 256; off <<= 1) {
        int x = (t >= off) ? s[t - off] : 0;
        __syncthreads();
        s[t] += x;
        __syncthreads();
    }
    const int off_l = s[t] - dv;
    if (n < N_NODES) {
        rowptr[n] = base + off_l;
        deg[n]    = dv;
    }
    cur[t] = off_l;
    __syncthreads();

    for (int i = t; i < cnt; i += 256) {
        unsigned int ed = pe[base + i];
        int pos = atomicAdd(&cur[ed & 255u], 1);
        sorted_src[base + pos] = (int)(ed >> 8);
    }
}

// ---------------------------------------------------------------------------
// Pull aggregation, H=4, D=32, bf16 gathers, wave per node. bf16 residual in,
// bf16 out (hidden-layer activations are bf16 end-to-end).
// ---------------------------------------------------------------------------
__global__ __launch_bounds__(256) void gat_agg128(const int* __restrict__ rowptr,
                                                  const int* __restrict__ deg,
                                                  const int* __restrict__ sorted_src,
                                                  const float* __restrict__ el,
                                                  const float* __restrict__ er,
                                                  const unsigned short* __restrict__ featb,
                                                  const unsigned short* __restrict__ resb,
                                                  unsigned short* __restrict__ outb) {
    __shared__ int   sS[4][64];
    __shared__ float sW[4][64][4];

    const int wv   = threadIdx.x >> 6;
    const int lane = threadIdx.x & 63;
    const int nd   = blockIdx.x * 4 + wv;

    const int dg = deg[nd];
    const int r0 = rowptr[nd];
    const int h  = lane >> 4;
    const float4 er4 = *(const float4*)(er + nd * 4);

    float den = 0.f;
    float ax = 0.f, ay = 0.f;

    for (int base = 0; base < dg; base += 64) {
        int m = dg - base; if (m > 64) m = 64;
        if (lane < m) {
            int s = sorted_src[r0 + base + lane];
            sS[wv][lane] = s;
            float4 e4 = *(const float4*)(el + s * 4);
            float4 w;
            float v;
            v = e4.x + er4.x; v = v > 0.f ? v : NEG_SLOPE * v; w.x = __expf(v);
            v = e4.y + er4.y; v = v > 0.f ? v : NEG_SLOPE * v; w.y = __expf(v);
            v = e4.z + er4.z; v = v > 0.f ? v : NEG_SLOPE * v; w.z = __expf(v);
            v = e4.w + er4.w; v = v > 0.f ? v : NEG_SLOPE * v; w.w = __expf(v);
            *(float4*)(&sW[wv][lane][0]) = w;
        }
        // wave-synchronous: same wave wrote LDS
        for (int i = 0; i < m; ++i) {
            int s   = sS[wv][i];
            float w = sW[wv][i][h];
            den += w;
            ushort2 u = *(const ushort2*)(featb + (size_t)s * 128 + lane * 2);
            ax += w * bf2f(u.x);
            ay += w * bf2f(u.y);
        }
    }

    float scale = den > 0.f ? 1.f / den : 0.f;
    float ox = ax * scale, oy = ay * scale;
    size_t o0 = (size_t)nd * 128 + lane * 2;
    if (resb) {
        ushort2 rv = *(const ushort2*)(resb + o0);
        ox += bf2f(rv.x);
        oy += bf2f(rv.y);
    }
    ox = fmaxf(ox, 0.f);
    oy = fmaxf(oy, 0.f);
    ushort2 ou;
    ou.x = f2bf(ox);
    ou.y = f2bf(oy);
    *(ushort2*)(outb + o0) = ou;
}

// ---------------------------------------------------------------------------
// Pull aggregation, H=1, C=16: wave per node, LDS staging, 8 edge-groups of
// 8 lanes; lane owns a feature pair. Final output f32 (+res2).
// ---------------------------------------------------------------------------
__global__ __launch_bounds__(256) void gat_agg16(const int* __restrict__ rowptr,
                                                 const int* __restrict__ deg,
                                                 const int* __restrict__ sorted_src,
                                                 const float* __restrict__ el,
                                                 const float* __restrict__ er,
                                                 const unsigned short* __restrict__ feat2b,
                                                 const float* __restrict__ res,
                                                 float* __restrict__ out) {
    __shared__ int   sS[4][64];
    __shared__ float sW[4][64];

    const int wv   = threadIdx.x >> 6;
    const int lane = threadIdx.x & 63;
    const int nd   = blockIdx.x * 4 + wv;
    const int g    = lane >> 3;
    const int f2   = (lane & 7) * 2;

    const int dg = deg[nd];
    const int r0 = rowptr[nd];
    const float erd = er[nd];

    float ax = 0.f, ay = 0.f, den = 0.f;

    for (int base = 0; base < dg; base += 64) {
        int m = dg - base; if (m > 64) m = 64;
        if (lane < m) {
            int s = sorted_src[r0 + base + lane];
            sS[wv][lane] = s;
            float v = el[s] + erd;
            v = v > 0.f ? v : NEG_SLOPE * v;
            sW[wv][lane] = __expf(v);
        }
        for (int i = g; i < m; i += 8) {
            int s   = sS[wv][i];
            float w = sW[wv][i];
            den += w;
            ushort2 u = *(const ushort2*)(feat2b + (size_t)s * 16 + f2);
            ax += w * bf2f(u.x);
            ay += w * bf2f(u.y);
        }
    }

    ax += __shfl_down(ax, 32); ay += __shfl_down(ay, 32); den += __shfl_down(den, 32);
    ax += __shfl_down(ax, 16); ay += __shfl_down(ay, 16); den += __shfl_down(den, 16);
    ax += __shfl_down(ax, 8);  ay += __shfl_down(ay, 8);  den += __shfl_down(den, 8);

    if (lane < 8) {
        float scale = den > 0.f ? 1.f / den : 0.f;
        size_t o0 = (size_t)nd * 16 + f2;
        float2 o;
        o.x = ax * scale + res[o0];
        o.y = ay * scale + res[o0 + 1];
        *(float2*)(out + o0) = o;
    }
}

// ---------------------------------------------------------------------------
extern "C" void kernel_launch(void* const* d_in, const int* in_sizes, int n_in,
                              void* d_out, int out_size, void* d_ws, size_t ws_size,
                              hipStream_t stream) {
    const float* inputs = (const float*)d_in[0];
    const int*   src    = (const int*)d_in[1];
    const int*   dst    = (const int*)d_in[2];
    const float* W0     = (const float*)d_in[3];
    const float* al0    = (const float*)d_in[4];
    const float* ar0    = (const float*)d_in[5];
    const float* W1     = (const float*)d_in[6];
    const float* al1    = (const float*)d_in[7];
    const float* ar1    = (const float*)d_in[8];
    const float* W2     = (const float*)d_in[9];
    const float* al2    = (const float*)d_in[10];
    const float* ar2    = (const float*)d_in[11];
    const float* resW2  = (const float*)d_in[12];
    float* out = (float*)d_out;

    const size_t NF = (size_t)N_NODES * 128;
    float* ws   = (float*)d_ws;
    float* el   = ws;                                  // N*4
    float* er   = el + (size_t)N_NODES * 4;            // N*4
    float* res2 = er + (size_t)N_NODES * 4;            // N*16
    unsigned short* hbufb  = (unsigned short*)(res2 + (size_t)N_NODES * 16);  // N*128 bf16
    unsigned short* featb  = hbufb + NF;               // N*128 bf16
    unsigned short* feat2b = featb + NF;               // N*16 bf16
    unsigned short* W0p    = feat2b + (size_t)N_NODES * 16;  // 16384
    unsigned short* W1p    = W0p + 16384;                    // 16384
    unsigned short* W2p    = W1p + 16384;                    // 8192
    int* iws = (int*)(W2p + 8192);
    unsigned int* pe = (unsigned int*)iws;             // E uint (packed)
    int* deg         = iws + N_EDGES;                  // N
    int* rowptr      = deg + N_NODES;                  // N
    int* sorted_src  = rowptr + N_NODES;               // E
    int* bcount      = sorted_src + N_EDGES;           // 512
    int* bbase       = bcount + NBUCK;                 // 512
    int* bcursor     = bbase + NBUCK;                  // 512

    dim3 blk(256);
    int gemmGrid = (N_NODES + 63) / 64;
    int pGrid    = (N_EDGES + PCHUNK - 1) / PCHUNK;    // 391
    int bGrid    = (N_NODES + 255) / 256;              // 391
    int aggGrid  = N_NODES / 4;                        // 25000

    // ---------------- CSR build + weight pack ------------------------------
    hipMemsetAsync(bcount, 0, NBUCK * sizeof(int), stream);
    bucket_count_k<<<pGrid, blk, 0, stream>>>(dst, bcount, N_EDGES);
    scan512<<<1, NBUCK, 0, stream>>>(bcount, bbase, bcursor);
    partition_k<<<pGrid, dim3(512), 0, stream>>>(src, dst, bcursor, pe, N_EDGES);
    bucket_finalize<<<bGrid, blk, 0, stream>>>(pe, bbase, rowptr, deg, sorted_src, N_EDGES);
    pack_all<<<160, blk, 0, stream>>>(W0, W1, W2, resW2, W0p, W1p, W2p);

    // ---------------- layer 0 ----------------
    gemm128_mfma_f32<<<gemmGrid, blk, 0, stream>>>(inputs, W0p, al0, ar0, featb,
                                                   el, er, N_NODES);
    gat_agg128<<<aggGrid, blk, 0, stream>>>(rowptr, deg, sorted_src, el, er, featb,
                                            nullptr, hbufb);

    // ---------------- layer 1 ----------------
    gemm128_mfma_bf16<<<gemmGrid, blk, 0, stream>>>(hbufb, W1p, al1, ar1, featb,
                                                    el, er, N_NODES);
    gat_agg128<<<aggGrid, blk, 0, stream>>>(rowptr, deg, sorted_src, el, er, featb,
                                            hbufb, hbufb);

    // ---------------- layer 2 ----------------
    gemm16_mfma<<<gemmGrid, blk, 0, stream>>>(hbufb, W2p, al2, ar2, feat2b, res2,
                                              el, er, N_NODES);
    gat_agg16<<<aggGrid, blk, 0, stream>>>(rowptr, deg, sorted_src, el, er, feat2b,
                                           res2, out);
}